// Round 9
// baseline (378.642 us; speedup 1.0000x reference)
//
#include <hip/hip_runtime.h>
#include <math.h>

#define NHEAD 4
#define BATCH 16
#define SEQ   2048
#define DMODEL 128
#define NTYPES 5
#define BAND  64
#define MROWS (BATCH * SEQ)  // 32768
#define NCHUNK 256           // 128-row chunks
#define CROWS 128

typedef __attribute__((ext_vector_type(8))) short bf16x8;
typedef __attribute__((ext_vector_type(4))) float f32x4;
typedef __attribute__((ext_vector_type(4))) unsigned int u32x4;

static __device__ __forceinline__ unsigned short f2bf(float f) {
  unsigned int u = __float_as_uint(f);
  unsigned int r = (u + 0x7fffu + ((u >> 16) & 1u)) >> 16;  // RNE
  return (unsigned short)r;
}
static __device__ __forceinline__ float bflo(unsigned int v) {
  return __uint_as_float(v << 16);
}
static __device__ __forceinline__ float bfhi(unsigned int v) {
  return __uint_as_float(v & 0xffff0000u);
}
static __device__ __forceinline__ unsigned int pkbf(float lo, float hi) {
  return ((unsigned int)f2bf(hi) << 16) | (unsigned int)f2bf(lo);
}
static __device__ __forceinline__ int xcd_swz(int blk, int nwg) {
  return (blk & 7) * (nwg >> 3) + (blk >> 3);
}

// ---------------------------------------------------------------------------
// init (tiny): W3 -> bf16, g table, zero sum_head, zero flags. grid 128x256.
// ---------------------------------------------------------------------------
__global__ __launch_bounds__(256) void init_kernel(
    const float* __restrict__ corm,  // [T,D]
    const int* __restrict__ et,      // [B,S]
    const float* __restrict__ W3,    // [H,D,D]
    unsigned short* __restrict__ wbf,   // [H,D,D] bf16
    float* __restrict__ gbuf,           // [B*S]
    float* __restrict__ sum_head,       // [B*D]
    unsigned int* __restrict__ flags) { // [H*NCHUNK]
  __shared__ float rowmean[NTYPES];
  const int tid = threadIdx.x;
  const long t = (long)blockIdx.x * 256 + tid;

  if (t < (NHEAD * DMODEL * DMODEL) / 8) {  // convert W3: 8192 threads x 8
    const long u = t * 8;
    float4 a = *reinterpret_cast<const float4*>(W3 + u);
    float4 b = *reinterpret_cast<const float4*>(W3 + u + 4);
    unsigned short o[8];
    o[0] = f2bf(a.x); o[1] = f2bf(a.y); o[2] = f2bf(a.z); o[3] = f2bf(a.w);
    o[4] = f2bf(b.x); o[5] = f2bf(b.y); o[6] = f2bf(b.z); o[7] = f2bf(b.w);
    *reinterpret_cast<u32x4*>(wbf + u) = *reinterpret_cast<u32x4*>(o);
  }
  if (tid < NTYPES) {
    float s = 0.f;
    for (int d = 0; d < DMODEL; ++d) s += corm[tid * DMODEL + d];
    rowmean[tid] = s * (1.0f / DMODEL);
  }
  __syncthreads();
  if (t < MROWS) gbuf[t] = rowmean[et[t] - 1];
  if (t < BATCH * DMODEL) sum_head[t] = 0.f;
  if (t < NHEAD * NCHUNK) flags[t] = 0u;
}

// ---------------------------------------------------------------------------
// persistent kernel: grid 256 x 1024 thr. Block owns global rows
// [R0, R0+128) for all 4 heads. LDS 105216 B (>80KB => 1 block/CU forced =>
// all 256 blocks co-resident => neighbor flag-spin is deadlock-free).
// Per head: stage W -> MFMA(Xl,Wl) -> z to LDS -> export first 64 z rows
// (halo for chunk-1) + release flag -> acquire neighbor flag + import halo
// -> band window-sum (s8 partials + slide) -> corr into Xl (next X) +
// f32 cs/hs register accumulation. Final head writes ss f32; one hred
// reduce + atomics for head_out at the end.
// LDS: Xl[0,34816) 128x272 | zl[34816,84736) 192 rows x 65 u32 (Wl aliases
// first 34816 of zl, barrier-separated) | s8[84736,97024) | hred[97024,105216).
// ---------------------------------------------------------------------------
__global__ __launch_bounds__(1024) void persist_kernel(
    const float* __restrict__ x0,           // [32768][128] f32
    const unsigned short* __restrict__ wbf, // [4][128][128] bf16
    const float* __restrict__ b3,           // [4][128]
    const float* __restrict__ gbuf,         // [B*S]
    unsigned short* __restrict__ zh,        // [4][256][64][128] bf16 halo
    unsigned int* __restrict__ flags,       // [4][256]
    float* __restrict__ SS,                 // [32768][128] f32
    float* __restrict__ SH) {               // [B][128]
  __shared__ __align__(16) char lds[105216];
  char* Xl = lds;                                                   // 128x272
  unsigned int* zl = reinterpret_cast<unsigned int*>(lds + 34816);  // [192]x65
  char* Wl = lds + 34816;                                           // alias
  float2* s8 = reinterpret_cast<float2*>(lds + 84736);              // [24][64]
  float* hred = reinterpret_cast<float*>(lds + 97024);              // [64][16][2]

  const int tid = threadIdx.x;
  const int chunk = xcd_swz(blockIdx.x, gridDim.x);  // grid 256
  const long R0 = (long)chunk * CROWS;
  const int bb = (int)(R0 >> 11);
  const int s0 = (int)(R0 & 2047);
  const bool has_halo = ((chunk & 15) != 15);  // last chunk of batch: none

  const int p = tid & 63, q = tid >> 6;        // band mapping
  const int l = tid & 63;                      // MFMA mapping (wave q)
  const int mv = q >> 1, nh = q & 1;
  const int lr = l & 15, lk = l >> 4;

  // ---- stage X0 (head 0): 128 rows f32 -> bf16 Xl
  #pragma unroll
  for (int it = 0; it < 2; ++it) {
    const int u = it * 1024 + tid;
    const int r = u >> 4, g4 = u & 15;
    const float* xs = x0 + (R0 + r) * DMODEL + g4 * 8;
    float4 f0 = *reinterpret_cast<const float4*>(xs);
    float4 f1 = *reinterpret_cast<const float4*>(xs + 4);
    unsigned short o[8];
    o[0] = f2bf(f0.x); o[1] = f2bf(f0.y); o[2] = f2bf(f0.z); o[3] = f2bf(f0.w);
    o[4] = f2bf(f1.x); o[5] = f2bf(f1.y); o[6] = f2bf(f1.z); o[7] = f2bf(f1.w);
    *reinterpret_cast<u32x4*>(Xl + r * 272 + g4 * 16) =
        *reinterpret_cast<u32x4*>(o);
  }

  float cs0[8], cs1[8];  // running sum_seq, f32, fixed rows q*8..q*8+8
  #pragma unroll
  for (int i = 0; i < 8; ++i) { cs0[i] = 0.f; cs1[i] = 0.f; }
  float hs0 = 0.f, hs1 = 0.f;
  const float* gr = gbuf + (long)bb * SEQ + s0;

  for (int h = 0; h < NHEAD; ++h) {
    // ---- stage W_h (writes Wl = zl alias; prev band done via loop barrier)
    #pragma unroll
    for (int it = 0; it < 2; ++it) {
      const int u = it * 1024 + tid;
      const int e = u >> 4, g4 = u & 15;
      u32x4 v = *reinterpret_cast<const u32x4*>(
          wbf + (long)h * DMODEL * DMODEL + e * DMODEL + g4 * 8);
      *reinterpret_cast<u32x4*>(Wl + e * 272 + g4 * 16) = v;
    }
    __syncthreads();  // Xl + Wl ready

    // ---- MFMA: 16 waves = 8 M-groups x 2 N-halves
    f32x4 acc[4];
    #pragma unroll
    for (int n = 0; n < 4; ++n) acc[n] = (f32x4){0.f, 0.f, 0.f, 0.f};
    #pragma unroll
    for (int t = 0; t < 4; ++t) {
      const bf16x8 a = *reinterpret_cast<const bf16x8*>(
          Xl + (mv * 16 + lr) * 272 + (t * 4 + lk) * 16);
      #pragma unroll
      for (int n = 0; n < 4; ++n) {
        const bf16x8 bfr = *reinterpret_cast<const bf16x8*>(
            Wl + (nh * 64 + n * 16 + lr) * 272 + (t * 4 + lk) * 16);
        acc[n] = __builtin_amdgcn_mfma_f32_16x16x32_bf16(a, bfr, acc[n], 0, 0, 0);
      }
    }
    __syncthreads();  // Wl dead -> zl writable

    // ---- epilogue: +bias, ELU -> zl rows [0,128)
    const float* bv = b3 + h * DMODEL;
    #pragma unroll
    for (int n = 0; n < 4; ++n) {
      const int col = nh * 64 + n * 16 + lr;
      const float bias = bv[col];
      #pragma unroll
      for (int r = 0; r < 4; ++r) {
        const int row = mv * 16 + lk * 4 + r;
        float v = acc[n][r] + bias;
        const float e = expm1f(fminf(v, 0.f));
        v = v > 0.f ? v : e;
        *reinterpret_cast<unsigned short*>(
            reinterpret_cast<char*>(zl) + row * 260 + col * 2) = f2bf(v);
      }
    }
    __syncthreads();  // zl rows [0,128) complete

    // ---- export own first 64 rows -> zh[h][chunk] (halo for chunk-1)
    {
      const int r = tid >> 4, c4 = tid & 15;
      unsigned int w4[4];
      #pragma unroll
      for (int k = 0; k < 4; ++k) w4[k] = zl[r * 65 + c4 * 4 + k];
      *reinterpret_cast<u32x4*>(
          zh + (((long)h * NCHUNK + chunk) * 64 + r) * DMODEL + c4 * 8) =
          *reinterpret_cast<u32x4*>(w4);
    }
    __threadfence();
    __syncthreads();
    if (tid == 0)
      __hip_atomic_store(flags + h * NCHUNK + chunk, 1u, __ATOMIC_RELEASE,
                         __HIP_MEMORY_SCOPE_AGENT);

    // ---- import halo rows [128,192) from chunk+1 (same batch)
    if (has_halo) {
      if (tid == 0) {
        while (__hip_atomic_load(flags + h * NCHUNK + chunk + 1,
                                 __ATOMIC_ACQUIRE,
                                 __HIP_MEMORY_SCOPE_AGENT) == 0u)
          __builtin_amdgcn_s_sleep(2);
      }
      __syncthreads();
      const int r = tid >> 4, c4 = tid & 15;
      const unsigned int* src = reinterpret_cast<const unsigned int*>(
          zh + (((long)h * NCHUNK + chunk + 1) * 64 + r) * DMODEL) + c4 * 4;
      #pragma unroll
      for (int k = 0; k < 4; ++k) {
        const unsigned int v = __hip_atomic_load(src + k, __ATOMIC_RELAXED,
                                                 __HIP_MEMORY_SCOPE_AGENT);
        zl[(128 + r) * 65 + c4 * 4 + k] = v;
      }
    } else {
      const int r = tid >> 4, c4 = tid & 15;
      #pragma unroll
      for (int k = 0; k < 4; ++k) zl[(128 + r) * 65 + c4 * 4 + k] = 0u;
    }
    __syncthreads();

    // ---- s8 partials: 24 groups of 8 rows; thread-group q does q (+16+q if q<8)
    {
      float a0 = 0.f, a1 = 0.f;
      #pragma unroll
      for (int jr = 0; jr < 8; ++jr) {
        const unsigned int v = zl[(q * 8 + jr) * 65 + p];
        a0 += bflo(v); a1 += bfhi(v);
      }
      s8[q * 64 + p] = make_float2(a0, a1);
      if (q < 8) {
        float b0 = 0.f, b1 = 0.f;
        #pragma unroll
        for (int jr = 0; jr < 8; ++jr) {
          const unsigned int v = zl[((16 + q) * 8 + jr) * 65 + p];
          b0 += bflo(v); b1 += bfhi(v);
        }
        s8[(16 + q) * 64 + p] = make_float2(b0, b1);
      }
    }
    __syncthreads();

    // ---- initial window for row q*8: s8 groups [q, q+8)
    float w0 = 0.f, w1 = 0.f;
    #pragma unroll
    for (int j = 0; j < 8; ++j) {
      const float2 v = s8[(q + j) * 64 + p];
      w0 += v.x; w1 += v.y;
    }

    // ---- slide: 8 outputs/thread; corr -> Xl (next X) or ss (last head)
    const int last = (h == NHEAD - 1) ? 1 : 0;
    #pragma unroll
    for (int i = 0; i < 8; ++i) {
      const int s = q * 8 + i;
      const float c0v = w0, c1v = w1;
      const float g = gr[s];
      hs0 += c0v * g; hs1 += c1v * g;
      cs0[i] += c0v; cs1[i] += c1v;
      if (!last) {
        *reinterpret_cast<unsigned int*>(Xl + s * 272 + p * 4) = pkbf(c0v, c1v);
      } else {
        float2 o; o.x = cs0[i]; o.y = cs1[i];
        *reinterpret_cast<float2*>(SS + (R0 + s) * DMODEL + 2 * p) = o;
      }
      const unsigned int va = zl[(s + BAND) * 65 + p];
      const unsigned int vs = zl[s * 65 + p];
      w0 += bflo(va) - bflo(vs);
      w1 += bfhi(va) - bfhi(vs);
    }
    __syncthreads();  // Xl ready; zl/s8 free for next head's W-stage
  }

  // ---- head_out reduce (summed over all heads) -> 2 atomics per (b, d-pair)
  *reinterpret_cast<float2*>(hred + (p * 16 + q) * 2) = make_float2(hs0, hs1);
  __syncthreads();
  if (q == 0) {
    float t0 = 0.f, t1 = 0.f;
    #pragma unroll
    for (int k = 0; k < 16; ++k) {
      const float2 v = *reinterpret_cast<const float2*>(hred + (p * 16 + k) * 2);
      t0 += v.x; t1 += v.y;
    }
    atomicAdd(SH + bb * DMODEL + 2 * p, t0);
    atomicAdd(SH + bb * DMODEL + 2 * p + 1, t1);
  }
}

// ---------------------------------------------------------------------------
extern "C" void kernel_launch(void* const* d_in, const int* in_sizes, int n_in,
                              void* d_out, int out_size, void* d_ws, size_t ws_size,
                              hipStream_t stream) {
  const float* x0   = (const float*)d_in[0];
  // d_in[1] = local_cor (banded mask) -- structure known analytically, unused
  const float* corm = (const float*)d_in[2];
  const int*   et   = (const int*)d_in[3];
  const float* W3   = (const float*)d_in[4];
  const float* b3   = (const float*)d_in[5];

  float* out_ss = (float*)d_out;
  float* out_sh = out_ss + (size_t)MROWS * DMODEL;

  char* ws = (char*)d_ws;
  const size_t MB = 1024 * 1024;
  unsigned short* zh   = (unsigned short*)ws;                   // 16 MB
  unsigned short* wbf  = (unsigned short*)(ws + 16 * MB);       // 128 KB
  float*          gbuf = (float*)(ws + 16 * MB + 131072);       // 128 KB
  unsigned int*   flags = (unsigned int*)(ws + 16 * MB + 262144);  // 4 KB

  init_kernel<<<128, 256, 0, stream>>>(corm, et, W3, wbf, gbuf, out_sh, flags);
  persist_kernel<<<NCHUNK, 1024, 0, stream>>>(
      x0, wbf, b3, gbuf, zh, flags, out_ss, out_sh);
}

// Round 10
// 178.090 us; speedup vs baseline: 2.1261x; 2.1261x over previous
//
#include <hip/hip_runtime.h>
#include <hip/hip_cooperative_groups.h>
#include <math.h>

namespace cg = cooperative_groups;

#define NHEAD 4
#define BATCH 16
#define SEQ   2048
#define DMODEL 128
#define NTYPES 5
#define BAND  64
#define MROWS (BATCH * SEQ)  // 32768
#define NCHUNK 256           // 128-row chunks
#define CROWS 128

typedef __attribute__((ext_vector_type(8))) short bf16x8;
typedef __attribute__((ext_vector_type(4))) float f32x4;
typedef __attribute__((ext_vector_type(4))) unsigned int u32x4;

static __device__ __forceinline__ unsigned short f2bf(float f) {
  unsigned int u = __float_as_uint(f);
  unsigned int r = (u + 0x7fffu + ((u >> 16) & 1u)) >> 16;  // RNE
  return (unsigned short)r;
}
static __device__ __forceinline__ float bflo(unsigned int v) {
  return __uint_as_float(v << 16);
}
static __device__ __forceinline__ float bfhi(unsigned int v) {
  return __uint_as_float(v & 0xffff0000u);
}
static __device__ __forceinline__ unsigned int pkbf(float lo, float hi) {
  return ((unsigned int)f2bf(hi) << 16) | (unsigned int)f2bf(lo);
}
static __device__ __forceinline__ int xcd_swz(int blk, int nwg) {
  return (blk & 7) * (nwg >> 3) + (blk >> 3);
}

// ---------------------------------------------------------------------------
// single cooperative persistent kernel: grid 256 x 1024 thr, 1 block/CU
// (LDS >80KB). Block owns rows [R0, R0+128) for the whole head chain.
// Per head: stage W_h (f32->bf16 inline, Wl aliases zl) -> MFMA -> z to LDS
// -> export top 64 z rows to zh[h][chunk] -> grid.sync() -> import halo
// rows [128,192) from zh[h][chunk+1] -> band (s8 + slide) -> corr into Xl,
// f32 cs/hs register accumulation. Head 3 writes ss f32; epilogue reduces
// head_out -> atomics. No flags, no per-poll fences: 4 grid syncs total.
// LDS: Xl[0,34816) 128x272 | zl[34816,84736) [192]x65 u32 (Wl aliases head
// of zl, barrier-separated) | s8[84736,97024) [24][64]f2 | hred[97024,105216).
// ---------------------------------------------------------------------------
__global__ __launch_bounds__(1024) void persist_kernel(
    const float* __restrict__ x0,    // [32768][128] f32
    const float* __restrict__ W3,    // [4][128][128] f32
    const float* __restrict__ b3,    // [4][128] f32
    const float* __restrict__ corm,  // [5][128] f32
    const int* __restrict__ et,      // [16][2048] int
    unsigned short* __restrict__ zh, // [4][256][64][128] bf16 halo
    float* __restrict__ SS,          // [32768][128] f32
    float* __restrict__ SH) {        // [16][128] f32
  cg::grid_group grid = cg::this_grid();

  __shared__ __align__(16) char lds[105216];
  __shared__ float g_lds[CROWS];
  __shared__ float rowmean[NTYPES];
  char* Xl = lds;                                                   // 128x272
  unsigned int* zl = reinterpret_cast<unsigned int*>(lds + 34816);  // [192]x65
  char* Wl = lds + 34816;                                           // alias
  float2* s8 = reinterpret_cast<float2*>(lds + 84736);              // [24][64]
  float* hred = reinterpret_cast<float*>(lds + 97024);              // [64][16][2]

  const int tid = threadIdx.x;
  const int chunk = xcd_swz(blockIdx.x, gridDim.x);  // grid 256
  const long R0 = (long)chunk * CROWS;
  const int bb = (int)(R0 >> 11);
  const int s0 = (int)(R0 & 2047);
  const bool has_halo = ((chunk & 15) != 15);  // last chunk of batch: none

  const int p = tid & 63, q = tid >> 6;  // band/reduce mapping (q = 0..15)
  const int l = tid & 63;                // MFMA mapping (wave q)
  const int mv = q >> 1, nh = q & 1;
  const int lr = l & 15, lk = l >> 4;

  // ---- prologue: stage x0 (f32 -> bf16 Xl), rowmean, SH zero, g table ----
  #pragma unroll
  for (int it = 0; it < 2; ++it) {
    const int u = it * 1024 + tid;
    const int r = u >> 4, g4 = u & 15;
    const float* xs = x0 + (R0 + r) * DMODEL + g4 * 8;
    float4 f0 = *reinterpret_cast<const float4*>(xs);
    float4 f1 = *reinterpret_cast<const float4*>(xs + 4);
    unsigned short o[8];
    o[0] = f2bf(f0.x); o[1] = f2bf(f0.y); o[2] = f2bf(f0.z); o[3] = f2bf(f0.w);
    o[4] = f2bf(f1.x); o[5] = f2bf(f1.y); o[6] = f2bf(f1.z); o[7] = f2bf(f1.w);
    *reinterpret_cast<u32x4*>(Xl + r * 272 + g4 * 16) =
        *reinterpret_cast<u32x4*>(o);
  }
  if (tid < NTYPES) {
    float s = 0.f;
    for (int d = 0; d < DMODEL; ++d) s += corm[tid * DMODEL + d];
    rowmean[tid] = s * (1.0f / DMODEL);
  }
  if (((chunk & 15) == 0) && tid < DMODEL) SH[bb * DMODEL + tid] = 0.f;
  __syncthreads();
  if (tid < CROWS) g_lds[tid] = rowmean[et[bb * SEQ + s0 + tid] - 1];
  // (g_lds consumed after several barriers below)

  float cs0[8], cs1[8];  // running sum_seq, f32, rows q*8 .. q*8+8
  #pragma unroll
  for (int i = 0; i < 8; ++i) { cs0[i] = 0.f; cs1[i] = 0.f; }
  float hs0 = 0.f, hs1 = 0.f;

  for (int h = 0; h < NHEAD; ++h) {
    // ---- stage W_h: f32 -> bf16 into Wl (aliases zl; prev band done) ----
    #pragma unroll
    for (int it = 0; it < 2; ++it) {
      const int u = it * 1024 + tid;
      const int e = u >> 4, g4 = u & 15;
      const float* wsrc = W3 + (long)h * DMODEL * DMODEL + e * DMODEL + g4 * 8;
      float4 f0 = *reinterpret_cast<const float4*>(wsrc);
      float4 f1 = *reinterpret_cast<const float4*>(wsrc + 4);
      unsigned short o[8];
      o[0] = f2bf(f0.x); o[1] = f2bf(f0.y); o[2] = f2bf(f0.z); o[3] = f2bf(f0.w);
      o[4] = f2bf(f1.x); o[5] = f2bf(f1.y); o[6] = f2bf(f1.z); o[7] = f2bf(f1.w);
      *reinterpret_cast<u32x4*>(Wl + e * 272 + g4 * 16) =
          *reinterpret_cast<u32x4*>(o);
    }
    __syncthreads();  // Xl + Wl ready

    // ---- MFMA: 16 waves = 8 M-groups x 2 N-halves ----
    f32x4 acc[4];
    #pragma unroll
    for (int n = 0; n < 4; ++n) acc[n] = (f32x4){0.f, 0.f, 0.f, 0.f};
    #pragma unroll
    for (int t = 0; t < 4; ++t) {
      const bf16x8 a = *reinterpret_cast<const bf16x8*>(
          Xl + (mv * 16 + lr) * 272 + (t * 4 + lk) * 16);
      #pragma unroll
      for (int n = 0; n < 4; ++n) {
        const bf16x8 bfr = *reinterpret_cast<const bf16x8*>(
            Wl + (nh * 64 + n * 16 + lr) * 272 + (t * 4 + lk) * 16);
        acc[n] = __builtin_amdgcn_mfma_f32_16x16x32_bf16(a, bfr, acc[n], 0, 0, 0);
      }
    }
    __syncthreads();  // Wl dead -> zl writable

    // ---- epilogue: +bias, ELU -> zl rows [0,128) (pitch 260 B) ----
    const float* bv = b3 + h * DMODEL;
    #pragma unroll
    for (int n = 0; n < 4; ++n) {
      const int col = nh * 64 + n * 16 + lr;
      const float bias = bv[col];
      #pragma unroll
      for (int r = 0; r < 4; ++r) {
        const int row = mv * 16 + lk * 4 + r;
        float v = acc[n][r] + bias;
        const float e = expm1f(fminf(v, 0.f));
        v = v > 0.f ? v : e;
        *reinterpret_cast<unsigned short*>(
            reinterpret_cast<char*>(zl) + row * 260 + col * 2) = f2bf(v);
      }
    }
    __syncthreads();  // zl rows [0,128) complete

    // ---- export own first 64 rows -> zh[h][chunk] (halo for chunk-1) ----
    {
      const int r = tid >> 4, c4 = tid & 15;
      unsigned int w4[4];
      #pragma unroll
      for (int k = 0; k < 4; ++k) w4[k] = zl[r * 65 + c4 * 4 + k];
      *reinterpret_cast<u32x4*>(
          zh + (((long)h * NCHUNK + chunk) * 64 + r) * DMODEL + c4 * 8) =
          *reinterpret_cast<u32x4*>(w4);
    }

    grid.sync();  // halo visible device-wide (single fence pair per stage)

    // ---- import halo rows [128,192) from chunk+1 (same batch) ----
    {
      const int r = tid >> 4, c4 = tid & 15;
      if (has_halo) {
        const u32x4 v = *reinterpret_cast<const u32x4*>(
            zh + (((long)h * NCHUNK + chunk + 1) * 64 + r) * DMODEL + c4 * 8);
        #pragma unroll
        for (int k = 0; k < 4; ++k) zl[(128 + r) * 65 + c4 * 4 + k] = v[k];
      } else {
        #pragma unroll
        for (int k = 0; k < 4; ++k) zl[(128 + r) * 65 + c4 * 4 + k] = 0u;
      }
    }
    __syncthreads();

    // ---- s8 partials: 24 groups of 8 rows ----
    {
      float a0 = 0.f, a1 = 0.f;
      #pragma unroll
      for (int jr = 0; jr < 8; ++jr) {
        const unsigned int v = zl[(q * 8 + jr) * 65 + p];
        a0 += bflo(v); a1 += bfhi(v);
      }
      s8[q * 64 + p] = make_float2(a0, a1);
      if (q < 8) {
        float b0 = 0.f, b1 = 0.f;
        #pragma unroll
        for (int jr = 0; jr < 8; ++jr) {
          const unsigned int v = zl[((16 + q) * 8 + jr) * 65 + p];
          b0 += bflo(v); b1 += bfhi(v);
        }
        s8[(16 + q) * 64 + p] = make_float2(b0, b1);
      }
    }
    __syncthreads();

    // ---- initial window for row q*8: s8 groups [q, q+8) ----
    float w0 = 0.f, w1 = 0.f;
    #pragma unroll
    for (int j = 0; j < 8; ++j) {
      const float2 v = s8[(q + j) * 64 + p];
      w0 += v.x; w1 += v.y;
    }

    // ---- slide: 8 outputs/thread; corr -> Xl (next X) or ss (last head) ----
    const int last = (h == NHEAD - 1) ? 1 : 0;
    #pragma unroll
    for (int i = 0; i < 8; ++i) {
      const int s = q * 8 + i;
      const float c0v = w0, c1v = w1;
      const float g = g_lds[s];
      hs0 += c0v * g; hs1 += c1v * g;
      cs0[i] += c0v; cs1[i] += c1v;
      if (!last) {
        *reinterpret_cast<unsigned int*>(Xl + s * 272 + p * 4) = pkbf(c0v, c1v);
      } else {
        float2 o; o.x = cs0[i]; o.y = cs1[i];
        *reinterpret_cast<float2*>(SS + (R0 + s) * DMODEL + 2 * p) = o;
      }
      const unsigned int va = zl[(s + BAND) * 65 + p];
      const unsigned int vs = zl[s * 65 + p];
      w0 += bflo(va) - bflo(vs);
      w1 += bfhi(va) - bfhi(vs);
    }
    __syncthreads();  // Xl ready; zl/s8 free for next head's W-stage
  }

  // ---- head_out reduce (all heads) -> 2 atomics per (b, d-pair) ----
  *reinterpret_cast<float2*>(hred + (p * 16 + q) * 2) = make_float2(hs0, hs1);
  __syncthreads();
  if (q == 0) {
    float t0 = 0.f, t1 = 0.f;
    #pragma unroll
    for (int k = 0; k < 16; ++k) {
      const float2 v = *reinterpret_cast<const float2*>(hred + (p * 16 + k) * 2);
      t0 += v.x; t1 += v.y;
    }
    atomicAdd(SH + bb * DMODEL + 2 * p, t0);
    atomicAdd(SH + bb * DMODEL + 2 * p + 1, t1);
  }
}

// ---------------------------------------------------------------------------
extern "C" void kernel_launch(void* const* d_in, const int* in_sizes, int n_in,
                              void* d_out, int out_size, void* d_ws, size_t ws_size,
                              hipStream_t stream) {
  const float* x0   = (const float*)d_in[0];
  // d_in[1] = local_cor (banded mask) -- structure known analytically, unused
  const float* corm = (const float*)d_in[2];
  const int*   et   = (const int*)d_in[3];
  const float* W3   = (const float*)d_in[4];
  const float* b3   = (const float*)d_in[5];

  float* out_ss = (float*)d_out;
  float* out_sh = out_ss + (size_t)MROWS * DMODEL;

  unsigned short* zh = (unsigned short*)d_ws;  // 16 MB halo buffers

  void* args[] = {(void*)&x0, (void*)&W3, (void*)&b3, (void*)&corm,
                  (void*)&et, (void*)&zh, (void*)&out_ss, (void*)&out_sh};
  hipLaunchCooperativeKernel((const void*)persist_kernel, dim3(NCHUNK),
                             dim3(1024), args, 0, stream);
}

// Round 11
// 65.190 us; speedup vs baseline: 5.8083x; 2.7318x over previous
//
#include <hip/hip_runtime.h>
#include <math.h>

#define NHEAD 4
#define BATCH 16
#define SEQ   2048
#define DMODEL 128
#define NTYPES 5
#define BAND  64
#define MROWS (BATCH * SEQ)  // 32768

typedef __attribute__((ext_vector_type(8))) short bf16x8;
typedef __attribute__((ext_vector_type(4))) float f32x4;
typedef __attribute__((ext_vector_type(4))) unsigned int u32x4;

static __device__ __forceinline__ unsigned short f2bf(float f) {
  unsigned int u = __float_as_uint(f);
  unsigned int r = (u + 0x7fffu + ((u >> 16) & 1u)) >> 16;  // RNE
  return (unsigned short)r;
}
static __device__ __forceinline__ float bflo(unsigned int v) {
  return __uint_as_float(v << 16);
}
static __device__ __forceinline__ float bfhi(unsigned int v) {
  return __uint_as_float(v & 0xffff0000u);
}
static __device__ __forceinline__ unsigned int pkbf(float lo, float hi) {
  return ((unsigned int)f2bf(hi) << 16) | (unsigned int)f2bf(lo);
}
static __device__ __forceinline__ int xcd_swz(int blk, int nwg) {
  return (blk & 7) * (nwg >> 3) + (blk >> 3);
}

// ---------------------------------------------------------------------------
// gemm0: Z0 = ELU(X0 @ W0^T + b0), X0/W0 f32 converted inline while staging.
// 512 thr (8 waves = 4 M x 2 N-halves), M=64, N=128, K=128. Also zeros SH.
// ---------------------------------------------------------------------------
__global__ __launch_bounds__(512, 4) void gemm0_kernel(
    const float* __restrict__ X0,     // [32768][128] f32
    const float* __restrict__ W3h,    // [128][128] f32 (head 0)
    const float* __restrict__ bvec,   // [128] f32
    unsigned short* __restrict__ Zb,  // [32768][128] bf16
    float* __restrict__ SH) {         // [16][128] -- zeroed here
  __shared__ __align__(16) char lds[64 * 272 + 128 * 272];  // 52224
  char* Xl = lds;
  char* Wl = lds + 64 * 272;
  const int tid = threadIdx.x;
  const int swz = xcd_swz(blockIdx.x, gridDim.x);  // grid 512
  const int row0 = swz * 64;

  if (blockIdx.x < 16 && tid < DMODEL) SH[blockIdx.x * DMODEL + tid] = 0.f;

  #pragma unroll
  for (int it = 0; it < 2; ++it) {
    const int u = it * 512 + tid;
    const int r = u >> 4, g4 = u & 15;
    const float* xs = X0 + (long)(row0 + r) * DMODEL + g4 * 8;
    float4 f0 = *reinterpret_cast<const float4*>(xs);
    float4 f1 = *reinterpret_cast<const float4*>(xs + 4);
    unsigned short o[8];
    o[0] = f2bf(f0.x); o[1] = f2bf(f0.y); o[2] = f2bf(f0.z); o[3] = f2bf(f0.w);
    o[4] = f2bf(f1.x); o[5] = f2bf(f1.y); o[6] = f2bf(f1.z); o[7] = f2bf(f1.w);
    *reinterpret_cast<u32x4*>(Xl + r * 272 + g4 * 16) = *reinterpret_cast<u32x4*>(o);
  }
  #pragma unroll
  for (int it = 0; it < 4; ++it) {
    const int u = it * 512 + tid;
    const int e = u >> 4, g4 = u & 15;
    const float* wsrc = W3h + e * DMODEL + g4 * 8;
    float4 f0 = *reinterpret_cast<const float4*>(wsrc);
    float4 f1 = *reinterpret_cast<const float4*>(wsrc + 4);
    unsigned short o[8];
    o[0] = f2bf(f0.x); o[1] = f2bf(f0.y); o[2] = f2bf(f0.z); o[3] = f2bf(f0.w);
    o[4] = f2bf(f1.x); o[5] = f2bf(f1.y); o[6] = f2bf(f1.z); o[7] = f2bf(f1.w);
    *reinterpret_cast<u32x4*>(Wl + e * 272 + g4 * 16) = *reinterpret_cast<u32x4*>(o);
  }
  __syncthreads();

  const int wv = tid >> 6, l = tid & 63;
  const int mv = wv >> 1, nh = wv & 1;
  const int lr = l & 15, lk = l >> 4;
  f32x4 acc[4];
  #pragma unroll
  for (int n = 0; n < 4; ++n) acc[n] = (f32x4){0.f, 0.f, 0.f, 0.f};
  #pragma unroll
  for (int t = 0; t < 4; ++t) {
    const bf16x8 a = *reinterpret_cast<const bf16x8*>(
        Xl + (mv * 16 + lr) * 272 + (t * 4 + lk) * 16);
    #pragma unroll
    for (int n = 0; n < 4; ++n) {
      const bf16x8 bfrag = *reinterpret_cast<const bf16x8*>(
          Wl + (nh * 64 + n * 16 + lr) * 272 + (t * 4 + lk) * 16);
      acc[n] = __builtin_amdgcn_mfma_f32_16x16x32_bf16(a, bfrag, acc[n], 0, 0, 0);
    }
  }
  #pragma unroll
  for (int n = 0; n < 4; ++n) {
    const int col = nh * 64 + n * 16 + lr;
    const float bias = bvec[col];
    #pragma unroll
    for (int r = 0; r < 4; ++r) {
      const int row = row0 + mv * 16 + lk * 4 + r;
      float v = acc[n][r] + bias;
      const float e = expm1f(fminf(v, 0.f));
      v = v > 0.f ? v : e;
      Zb[(long)row * DMODEL + col] = f2bf(v);
    }
  }
}

// ---------------------------------------------------------------------------
// F_h: band(h) + gemm(h+1) fused.  grid 512, 512 thr. W from f32 inline;
// g computed per-block from et+corm. ACC=0: Cout=corr. ACC=1: Cout=CSin+corr.
// LDS 56320: Xl[0,17408) (s8 aliases first 8192 until post-window barrier);
// zl[17408,50176) (Wl[17408,52224) aliases after slide); hred[52224,56320).
// ---------------------------------------------------------------------------
template <int ACC>
__global__ __launch_bounds__(512, 4) void fused_band_gemm(
    const unsigned short* __restrict__ Zin,
    const unsigned short* __restrict__ CSin,
    unsigned short* __restrict__ Cout,
    const float* __restrict__ W3h,   // next head's W, f32
    const float* __restrict__ bvec,  // next head's bias, f32
    unsigned short* __restrict__ Zout,
    float* __restrict__ SH,
    const int* __restrict__ et,
    const float* __restrict__ corm) {
  __shared__ __align__(16) char lds[56320];
  __shared__ float g_lds[64];
  __shared__ float rowmean[NTYPES];
  char* Xl = lds;                                       // 64 x 272
  float2* s8 = reinterpret_cast<float2*>(lds);          // [16][64] alias
  unsigned int* zl = reinterpret_cast<unsigned int*>(lds + 17408);  // [128][64]
  char* Wl = lds + 17408;                               // 128 x 272 alias
  float* hred = reinterpret_cast<float*>(lds + 52224);  // [64][8][2]

  const int tid = threadIdx.x;
  const int swz = xcd_swz(blockIdx.x, gridDim.x);
  const int r0 = swz * 64;
  const int b = r0 >> 11, s0 = r0 & 2047;

  // ---- phase 1: stage z rows [s0, s0+128); rowmean; cs prefetch
  const unsigned int* zsrc = reinterpret_cast<const unsigned int*>(Zin) +
                             (long)b * SEQ * 64;
  #pragma unroll
  for (int it = 0; it < 4; ++it) {
    const int u = it * 512 + tid;
    const int r = u >> 4, c4 = u & 15;
    const int s = s0 + r;
    u32x4 v = (u32x4){0u, 0u, 0u, 0u};
    if (s < SEQ) v = *reinterpret_cast<const u32x4*>(zsrc + (long)s * 64 + c4 * 4);
    *reinterpret_cast<u32x4*>(zl + r * 64 + c4 * 4) = v;
  }
  if (tid < NTYPES) {
    float s = 0.f;
    for (int d = 0; d < DMODEL; ++d) s += corm[tid * DMODEL + d];
    rowmean[tid] = s * (1.0f / DMODEL);
  }
  const int p = tid & 63, q = tid >> 6;  // q = 0..7
  unsigned int csr[8];
  if (ACC) {
    #pragma unroll
    for (int i = 0; i < 8; ++i)
      csr[i] = *reinterpret_cast<const unsigned int*>(
          CSin + ((long)r0 + q * 8 + i) * DMODEL + 2 * p);
  }
  __syncthreads();

  // ---- phase 2: g table + s8 partials (16 groups of 8 rows)
  if (tid < 64) g_lds[tid] = rowmean[et[(long)b * SEQ + s0 + tid] - 1];
  #pragma unroll
  for (int j = 0; j < 2; ++j) {
    const int k = q * 2 + j;
    float a0 = 0.f, a1 = 0.f;
    #pragma unroll
    for (int jr = 0; jr < 8; ++jr) {
      const unsigned int v = zl[(k * 8 + jr) * 64 + p];
      a0 += bflo(v); a1 += bfhi(v);
    }
    s8[k * 64 + p] = make_float2(a0, a1);
  }
  __syncthreads();

  // ---- phase 3: initial window for row q*8: s8 groups [q, q+8)
  float w0 = 0.f, w1 = 0.f;
  #pragma unroll
  for (int j = 0; j < 8; ++j) {
    const float2 v = s8[(q + j) * 64 + p];
    w0 += v.x; w1 += v.y;
  }
  __syncthreads();  // s8 dead -> slide loop may write Xl (aliases s8)

  // ---- phase 4: slide, 8 outputs/thread; corr -> global + Xl
  float hs0 = 0.f, hs1 = 0.f;
  #pragma unroll
  for (int i = 0; i < 8; ++i) {
    const int s = q * 8 + i;
    const float c0v = w0, c1v = w1;
    const float g = g_lds[s];
    hs0 += c0v * g; hs1 += c1v * g;
    unsigned int pk;
    if (ACC)
      pk = pkbf(c0v + bflo(csr[i]), c1v + bfhi(csr[i]));
    else
      pk = pkbf(c0v, c1v);
    *reinterpret_cast<unsigned int*>(Cout + ((long)r0 + s) * DMODEL + 2 * p) = pk;
    *reinterpret_cast<unsigned int*>(Xl + s * 272 + p * 4) =
        ACC ? pkbf(c0v, c1v) : pk;
    const unsigned int va = zl[(s + BAND) * 64 + p];
    const unsigned int vs = zl[s * 64 + p];
    w0 += bflo(va) - bflo(vs);
    w1 += bfhi(va) - bfhi(vs);
  }
  *reinterpret_cast<float2*>(hred + (p * 8 + q) * 2) = make_float2(hs0, hs1);
  __syncthreads();   // zl reads done -> Wl may overwrite; hred visible

  // ---- phase 5: head_out reduce (q==0) + stage W (f32->bf16) into Wl
  if (q == 0) {
    float t0 = 0.f, t1 = 0.f;
    #pragma unroll
    for (int k = 0; k < 8; ++k) {
      const float2 v = *reinterpret_cast<const float2*>(hred + (p * 8 + k) * 2);
      t0 += v.x; t1 += v.y;
    }
    atomicAdd(SH + b * DMODEL + 2 * p, t0);
    atomicAdd(SH + b * DMODEL + 2 * p + 1, t1);
  }
  #pragma unroll
  for (int it = 0; it < 4; ++it) {
    const int u = it * 512 + tid;
    const int e = u >> 4, g4 = u & 15;
    const float* wsrc = W3h + e * DMODEL + g4 * 8;
    float4 f0 = *reinterpret_cast<const float4*>(wsrc);
    float4 f1 = *reinterpret_cast<const float4*>(wsrc + 4);
    unsigned short o[8];
    o[0] = f2bf(f0.x); o[1] = f2bf(f0.y); o[2] = f2bf(f0.z); o[3] = f2bf(f0.w);
    o[4] = f2bf(f1.x); o[5] = f2bf(f1.y); o[6] = f2bf(f1.z); o[7] = f2bf(f1.w);
    *reinterpret_cast<u32x4*>(Wl + e * 272 + g4 * 16) = *reinterpret_cast<u32x4*>(o);
  }
  __syncthreads();

  // ---- phase 6: MFMA on corr tile -> Zout (8 waves: 4 M x 2 N-halves)
  const int wv = tid >> 6, l = tid & 63;
  const int mv = wv >> 1, nh = wv & 1;
  const int lr = l & 15, lk = l >> 4;
  f32x4 acc[4];
  #pragma unroll
  for (int n = 0; n < 4; ++n) acc[n] = (f32x4){0.f, 0.f, 0.f, 0.f};
  #pragma unroll
  for (int t = 0; t < 4; ++t) {
    const bf16x8 a = *reinterpret_cast<const bf16x8*>(
        Xl + (mv * 16 + lr) * 272 + (t * 4 + lk) * 16);
    #pragma unroll
    for (int n = 0; n < 4; ++n) {
      const bf16x8 bfrag = *reinterpret_cast<const bf16x8*>(
          Wl + (nh * 64 + n * 16 + lr) * 272 + (t * 4 + lk) * 16);
      acc[n] = __builtin_amdgcn_mfma_f32_16x16x32_bf16(a, bfrag, acc[n], 0, 0, 0);
    }
  }
  #pragma unroll
  for (int n = 0; n < 4; ++n) {
    const int col = nh * 64 + n * 16 + lr;
    const float bias = bvec[col];
    #pragma unroll
    for (int r = 0; r < 4; ++r) {
      const int row = r0 + mv * 16 + lk * 4 + r;
      float v = acc[n][r] + bias;
      const float e = expm1f(fminf(v, 0.f));
      v = v > 0.f ? v : e;
      Zout[(long)row * DMODEL + col] = f2bf(v);
    }
  }
}

// ---------------------------------------------------------------------------
// f2final: band2 (128 rows) + gemm3 (128 rows, LDS-only z3) + band3 (64 rows)
// + ss = cs1 + corr2 + corr3 (all f32 adds).  grid 512 x 1024 thr, 1 blk/CU.
// LDS 140032: zst[0,49920) [192][65]u32 (z2, then z3 [128][65] after MFMA);
// Xl[49920,84736) corr2 128x272; Wl[84736,119552); s8[119552,131840) [24][64];
// hred[131840,140032) [64][16][2].
// ---------------------------------------------------------------------------
__global__ __launch_bounds__(1024) void f2final_kernel(
    const unsigned short* __restrict__ Zin,   // z2
    const unsigned short* __restrict__ CSin,  // cs1 = corr0+corr1
    const float* __restrict__ W3h,            // W3[3] f32
    const float* __restrict__ bvec,           // b3[3] f32
    float* __restrict__ SS,
    float* __restrict__ SH,
    const int* __restrict__ et,
    const float* __restrict__ corm) {
  __shared__ __align__(16) char lds[140032];
  __shared__ float g_lds[64];
  __shared__ float rowmean[NTYPES];
  unsigned int* zst = reinterpret_cast<unsigned int*>(lds);   // [192][65]
  char* Xl = lds + 49920;                                     // 128 x 272
  char* Wl = lds + 84736;                                     // 128 x 272
  float2* s8 = reinterpret_cast<float2*>(lds + 119552);       // [24][64]
  float* hred = reinterpret_cast<float*>(lds + 131840);       // [64][16][2]

  const int tid = threadIdx.x;
  const int swz = xcd_swz(blockIdx.x, gridDim.x);  // grid 512
  const int r0 = swz * 64;
  const int b = r0 >> 11, s0 = r0 & 2047;
  const int p = tid & 63, q = tid >> 6;  // q = 0..15

  // ---- phase 1: stage z2 rows [s0, s0+192); Wl (f32->bf16); rowmean; cs
  const unsigned int* zsrc = reinterpret_cast<const unsigned int*>(Zin) +
                             (long)b * SEQ * 64;
  #pragma unroll
  for (int it = 0; it < 3; ++it) {
    const int u = it * 1024 + tid;
    const int r = u >> 4, c4 = u & 15;
    const int s = s0 + r;
    u32x4 v = (u32x4){0u, 0u, 0u, 0u};
    if (s < SEQ) v = *reinterpret_cast<const u32x4*>(zsrc + (long)s * 64 + c4 * 4);
    *reinterpret_cast<u32x4*>(zst + r * 65 + c4 * 4) = v;
  }
  #pragma unroll
  for (int it = 0; it < 2; ++it) {
    const int u = it * 1024 + tid;
    const int e = u >> 4, g4 = u & 15;
    const float* wsrc = W3h + e * DMODEL + g4 * 8;
    float4 f0 = *reinterpret_cast<const float4*>(wsrc);
    float4 f1 = *reinterpret_cast<const float4*>(wsrc + 4);
    unsigned short o[8];
    o[0] = f2bf(f0.x); o[1] = f2bf(f0.y); o[2] = f2bf(f0.z); o[3] = f2bf(f0.w);
    o[4] = f2bf(f1.x); o[5] = f2bf(f1.y); o[6] = f2bf(f1.z); o[7] = f2bf(f1.w);
    *reinterpret_cast<u32x4*>(Wl + e * 272 + g4 * 16) = *reinterpret_cast<u32x4*>(o);
  }
  if (tid < NTYPES) {
    float s = 0.f;
    for (int d = 0; d < DMODEL; ++d) s += corm[tid * DMODEL + d];
    rowmean[tid] = s * (1.0f / DMODEL);
  }
  unsigned int csr[8];
  if (q < 8) {
    #pragma unroll
    for (int i = 0; i < 8; ++i)
      csr[i] = *reinterpret_cast<const unsigned int*>(
          CSin + ((long)r0 + q * 8 + i) * DMODEL + 2 * p);
  }
  __syncthreads();

  // ---- phase 2: g table + s8 partials over 192 rows (24 groups)
  if (tid < 64) g_lds[tid] = rowmean[et[(long)b * SEQ + s0 + tid] - 1];
  {
    float a0 = 0.f, a1 = 0.f;
    #pragma unroll
    for (int jr = 0; jr < 8; ++jr) {
      const unsigned int v = zst[(q * 8 + jr) * 65 + p];
      a0 += bflo(v); a1 += bfhi(v);
    }
    s8[q * 64 + p] = make_float2(a0, a1);
    if (q < 8) {
      float b0 = 0.f, b1 = 0.f;
      #pragma unroll
      for (int jr = 0; jr < 8; ++jr) {
        const unsigned int v = zst[((16 + q) * 8 + jr) * 65 + p];
        b0 += bflo(v); b1 += bfhi(v);
      }
      s8[(16 + q) * 64 + p] = make_float2(b0, b1);
    }
  }
  __syncthreads();

  // ---- phase 3: band2 over 128 rows; corr2 -> Xl; hs for own rows (q<8)
  float w0 = 0.f, w1 = 0.f;
  #pragma unroll
  for (int j = 0; j < 8; ++j) {
    const float2 v = s8[(q + j) * 64 + p];
    w0 += v.x; w1 += v.y;
  }
  float hs0 = 0.f, hs1 = 0.f;
  #pragma unroll
  for (int i = 0; i < 8; ++i) {
    const int s = q * 8 + i;
    const float c0v = w0, c1v = w1;
    if (q < 8) {
      const float g = g_lds[s];
      hs0 += c0v * g; hs1 += c1v * g;
    }
    *reinterpret_cast<unsigned int*>(Xl + s * 272 + p * 4) = pkbf(c0v, c1v);
    const unsigned int va = zst[(s + BAND) * 65 + p];
    const unsigned int vs = zst[s * 65 + p];
    w0 += bflo(va) - bflo(vs);
    w1 += bfhi(va) - bfhi(vs);
  }
  __syncthreads();  // Xl complete; zst dead

  // ---- phase 4: MFMA (16 waves: 8 M x 2 N-halves) -> z3 into zst region
  {
    const int l = tid & 63;
    const int mv = q >> 1, nh = q & 1;
    const int lr = l & 15, lk = l >> 4;
    f32x4 acc[4];
    #pragma unroll
    for (int n = 0; n < 4; ++n) acc[n] = (f32x4){0.f, 0.f, 0.f, 0.f};
    #pragma unroll
    for (int t = 0; t < 4; ++t) {
      const bf16x8 a = *reinterpret_cast<const bf16x8*>(
          Xl + (mv * 16 + lr) * 272 + (t * 4 + lk) * 16);
      #pragma unroll
      for (int n = 0; n < 4; ++n) {
        const bf16x8 bfrag = *reinterpret_cast<const bf16x8*>(
            Wl + (nh * 64 + n * 16 + lr) * 272 + (t * 4 + lk) * 16);
        acc[n] = __builtin_amdgcn_mfma_f32_16x16x32_bf16(a, bfrag, acc[n], 0, 0, 0);
      }
    }
    #pragma unroll
    for (int n = 0; n < 4; ++n) {
      const int col = nh * 64 + n * 16 + lr;
      const float bias = bvec[col];
      #pragma unroll
      for (int r = 0; r < 4; ++r) {
        const int row = mv * 16 + lk * 4 + r;
        float v = acc[n][r] + bias;
        const float e = expm1f(fminf(v, 0.f));
        v = v > 0.f ? v : e;
        const unsigned short bz =
            (s0 + row < SEQ) ? f2bf(v) : (unsigned short)0;
        *reinterpret_cast<unsigned short*>(
            reinterpret_cast<char*>(zst) + row * 260 + col * 2) = bz;
      }
    }
  }
  __syncthreads();  // z3 complete

  // ---- phase 5: s8 v2 over z3's 128 rows (16 groups)
  {
    float a0 = 0.f, a1 = 0.f;
    #pragma unroll
    for (int jr = 0; jr < 8; ++jr) {
      const unsigned int v = zst[(q * 8 + jr) * 65 + p];
      a0 += bflo(v); a1 += bfhi(v);
    }
    s8[q * 64 + p] = make_float2(a0, a1);
  }
  __syncthreads();

  // ---- phase 6: band3 own 64 rows (q<8); ss = cs1 + corr2 + corr3
  if (q < 8) {
    float v0 = 0.f, v1 = 0.f;
    #pragma unroll
    for (int j = 0; j < 8; ++j) {
      const float2 v = s8[(q + j) * 64 + p];
      v0 += v.x; v1 += v.y;
    }
    #pragma unroll
    for (int i = 0; i < 8; ++i) {
      const int s = q * 8 + i;
      const float c3l = v0, c3h = v1;
      const float g = g_lds[s];
      hs0 += c3l * g; hs1 += c3h * g;
      const unsigned int c2 =
          *reinterpret_cast<const unsigned int*>(Xl + s * 272 + p * 4);
      float2 o;
      o.x = c3l + bflo(c2) + bflo(csr[i]);
      o.y = c3h + bfhi(c2) + bfhi(csr[i]);
      *reinterpret_cast<float2*>(SS + ((long)r0 + s) * DMODEL + 2 * p) = o;
      const unsigned int va = zst[(s + BAND) * 65 + p];
      const unsigned int vs = zst[s * 65 + p];
      v0 += bflo(va) - bflo(vs);
      v1 += bfhi(va) - bfhi(vs);
    }
  }

  // ---- head_out reduce -> 2 atomics per (b, d-pair)
  *reinterpret_cast<float2*>(hred + (p * 16 + q) * 2) = make_float2(hs0, hs1);
  __syncthreads();
  if (q == 0) {
    float t0 = 0.f, t1 = 0.f;
    #pragma unroll
    for (int k = 0; k < 16; ++k) {
      const float2 v = *reinterpret_cast<const float2*>(hred + (p * 16 + k) * 2);
      t0 += v.x; t1 += v.y;
    }
    atomicAdd(SH + b * DMODEL + 2 * p, t0);
    atomicAdd(SH + b * DMODEL + 2 * p + 1, t1);
  }
}

// ---------------------------------------------------------------------------
extern "C" void kernel_launch(void* const* d_in, const int* in_sizes, int n_in,
                              void* d_out, int out_size, void* d_ws, size_t ws_size,
                              hipStream_t stream) {
  const float* x0   = (const float*)d_in[0];
  // d_in[1] = local_cor (banded mask) -- structure known analytically, unused
  const float* corm = (const float*)d_in[2];
  const int*   et   = (const int*)d_in[3];
  const float* W3   = (const float*)d_in[4];
  const float* b3   = (const float*)d_in[5];

  float* out_ss = (float*)d_out;
  float* out_sh = out_ss + (size_t)MROWS * DMODEL;

  char* ws = (char*)d_ws;
  const size_t MB = 1024 * 1024;
  unsigned short* A = (unsigned short*)(ws + 0 * MB);   // z0, then z2
  unsigned short* B = (unsigned short*)(ws + 8 * MB);   // corr0
  unsigned short* C = (unsigned short*)(ws + 16 * MB);  // cs1
  unsigned short* E = (unsigned short*)(ws + 24 * MB);  // z1

  const size_t WSTR = (size_t)DMODEL * DMODEL;

  // gemm0 (+SH zero): z0 = A
  gemm0_kernel<<<512, 512, 0, stream>>>(x0, W3, b3, A, out_sh);
  // F0: band0 (z0=A) -> corr0=B ; gemm1 -> z1=E
  fused_band_gemm<0><<<512, 512, 0, stream>>>(
      A, nullptr, B, W3 + 1 * WSTR, b3 + 1 * DMODEL, E, out_sh, et, corm);
  // F1: band1 (z1=E) -> cs1=C (=corr0+corr1) ; gemm2 -> z2=A
  fused_band_gemm<1><<<512, 512, 0, stream>>>(
      E, B, C, W3 + 2 * WSTR, b3 + 2 * DMODEL, A, out_sh, et, corm);
  // f2final: band2+gemm3+band3 ; ss = cs1 + corr2 + corr3 -> d_out
  f2final_kernel<<<512, 1024, 0, stream>>>(
      A, C, W3 + 3 * WSTR, b3 + 3 * DMODEL, out_ss, out_sh, et, corm);
}

// Round 12
// 62.122 us; speedup vs baseline: 6.0951x; 1.0494x over previous
//
#include <hip/hip_runtime.h>
#include <math.h>

#define NHEAD 4
#define BATCH 16
#define SEQ   2048
#define DMODEL 128
#define NTYPES 5
#define BAND  64
#define MROWS (BATCH * SEQ)  // 32768

typedef __attribute__((ext_vector_type(8))) short bf16x8;
typedef __attribute__((ext_vector_type(4))) float f32x4;
typedef __attribute__((ext_vector_type(4))) unsigned int u32x4;

static __device__ __forceinline__ unsigned short f2bf(float f) {
  unsigned int u = __float_as_uint(f);
  unsigned int r = (u + 0x7fffu + ((u >> 16) & 1u)) >> 16;  // RNE
  return (unsigned short)r;
}
static __device__ __forceinline__ float bflo(unsigned int v) {
  return __uint_as_float(v << 16);
}
static __device__ __forceinline__ float bfhi(unsigned int v) {
  return __uint_as_float(v & 0xffff0000u);
}
static __device__ __forceinline__ unsigned int pkbf(float lo, float hi) {
  return ((unsigned int)f2bf(hi) << 16) | (unsigned int)f2bf(lo);
}
static __device__ __forceinline__ int xcd_swz(int blk, int nwg) {
  return (blk & 7) * (nwg >> 3) + (blk >> 3);
}

// ---------------------------------------------------------------------------
// gemm0: Z0 = ELU(X0 @ W0^T + b0), X0/W0 f32 converted inline while staging.
// 512 thr (8 waves = 4 M x 2 N-halves), M=64, N=128, K=128. Also zeros SH.
// ---------------------------------------------------------------------------
__global__ __launch_bounds__(512, 4) void gemm0_kernel(
    const float* __restrict__ X0,     // [32768][128] f32
    const float* __restrict__ W3h,    // [128][128] f32 (head 0)
    const float* __restrict__ bvec,   // [128] f32
    unsigned short* __restrict__ Zb,  // [32768][128] bf16
    float* __restrict__ SH) {         // [16][128] -- zeroed here
  __shared__ __align__(16) char lds[64 * 272 + 128 * 272];  // 52224
  char* Xl = lds;
  char* Wl = lds + 64 * 272;
  const int tid = threadIdx.x;
  const int swz = xcd_swz(blockIdx.x, gridDim.x);  // grid 512
  const int row0 = swz * 64;

  if (blockIdx.x < 16 && tid < DMODEL) SH[blockIdx.x * DMODEL + tid] = 0.f;

  #pragma unroll
  for (int it = 0; it < 2; ++it) {
    const int u = it * 512 + tid;
    const int r = u >> 4, g4 = u & 15;
    const float* xs = X0 + (long)(row0 + r) * DMODEL + g4 * 8;
    float4 f0 = *reinterpret_cast<const float4*>(xs);
    float4 f1 = *reinterpret_cast<const float4*>(xs + 4);
    unsigned short o[8];
    o[0] = f2bf(f0.x); o[1] = f2bf(f0.y); o[2] = f2bf(f0.z); o[3] = f2bf(f0.w);
    o[4] = f2bf(f1.x); o[5] = f2bf(f1.y); o[6] = f2bf(f1.z); o[7] = f2bf(f1.w);
    *reinterpret_cast<u32x4*>(Xl + r * 272 + g4 * 16) = *reinterpret_cast<u32x4*>(o);
  }
  #pragma unroll
  for (int it = 0; it < 4; ++it) {
    const int u = it * 512 + tid;
    const int e = u >> 4, g4 = u & 15;
    const float* wsrc = W3h + e * DMODEL + g4 * 8;
    float4 f0 = *reinterpret_cast<const float4*>(wsrc);
    float4 f1 = *reinterpret_cast<const float4*>(wsrc + 4);
    unsigned short o[8];
    o[0] = f2bf(f0.x); o[1] = f2bf(f0.y); o[2] = f2bf(f0.z); o[3] = f2bf(f0.w);
    o[4] = f2bf(f1.x); o[5] = f2bf(f1.y); o[6] = f2bf(f1.z); o[7] = f2bf(f1.w);
    *reinterpret_cast<u32x4*>(Wl + e * 272 + g4 * 16) = *reinterpret_cast<u32x4*>(o);
  }
  __syncthreads();

  const int wv = tid >> 6, l = tid & 63;
  const int mv = wv >> 1, nh = wv & 1;
  const int lr = l & 15, lk = l >> 4;
  f32x4 acc[4];
  #pragma unroll
  for (int n = 0; n < 4; ++n) acc[n] = (f32x4){0.f, 0.f, 0.f, 0.f};
  #pragma unroll
  for (int t = 0; t < 4; ++t) {
    const bf16x8 a = *reinterpret_cast<const bf16x8*>(
        Xl + (mv * 16 + lr) * 272 + (t * 4 + lk) * 16);
    #pragma unroll
    for (int n = 0; n < 4; ++n) {
      const bf16x8 bfrag = *reinterpret_cast<const bf16x8*>(
          Wl + (nh * 64 + n * 16 + lr) * 272 + (t * 4 + lk) * 16);
      acc[n] = __builtin_amdgcn_mfma_f32_16x16x32_bf16(a, bfrag, acc[n], 0, 0, 0);
    }
  }
  #pragma unroll
  for (int n = 0; n < 4; ++n) {
    const int col = nh * 64 + n * 16 + lr;
    const float bias = bvec[col];
    #pragma unroll
    for (int r = 0; r < 4; ++r) {
      const int row = row0 + mv * 16 + lk * 4 + r;
      float v = acc[n][r] + bias;
      const float e = expm1f(fminf(v, 0.f));
      v = v > 0.f ? v : e;
      Zb[(long)row * DMODEL + col] = f2bf(v);
    }
  }
}

// ---------------------------------------------------------------------------
// F_h: band(h) + gemm(h+1), register-resident band. grid 512, 512 thr.
// Thread (p,q): zlo=rows[8q,8q+8), zhi=rows[8q+64,8q+72) -- feed BOTH the s8
// partials (groups q and q+8) and the slide add/sub. No z LDS tile.
// 3 barriers. ACC=0: Cout=corr. ACC=1: Cout=CSin+corr; Xl always raw corr.
// LDS 56320: Xl[0,17408) | Wl[17408,52224) (s8 aliases first 8192 until BAR2)
// | hred[52224,56320).
// ---------------------------------------------------------------------------
template <int ACC>
__global__ __launch_bounds__(512, 4) void fused_band_gemm(
    const unsigned short* __restrict__ Zin,
    const unsigned short* __restrict__ CSin,
    unsigned short* __restrict__ Cout,
    const float* __restrict__ W3h,   // next head's W, f32
    const float* __restrict__ bvec,  // next head's bias, f32
    unsigned short* __restrict__ Zout,
    float* __restrict__ SH,
    const int* __restrict__ et,
    const float* __restrict__ corm) {
  __shared__ __align__(16) char lds[56320];
  __shared__ float g_lds[64];
  __shared__ float rowmean[NTYPES];
  char* Xl = lds;                                          // [64][272]
  char* Wl = lds + 17408;                                  // [128][272]
  float2* s8 = reinterpret_cast<float2*>(lds + 17408);     // [16][64] alias
  float* hred = reinterpret_cast<float*>(lds + 52224);     // [64][8][2]

  const int tid = threadIdx.x;
  const int swz = xcd_swz(blockIdx.x, gridDim.x);
  const int r0 = swz * 64;
  const int b = r0 >> 11, s0 = r0 & 2047;
  const int p = tid & 63, q = tid >> 6;  // q = 0..7

  // ---- phase 1: ALL global reads issued up front ----
  const unsigned int* zsrc =
      reinterpret_cast<const unsigned int*>(Zin) + (long)b * SEQ * 64 + p;
  unsigned int zlo[8], zhi[8];
  #pragma unroll
  for (int i = 0; i < 8; ++i) {
    const int sl = s0 + q * 8 + i;
    zlo[i] = zsrc[(long)sl * 64];
    const int sh_ = sl + BAND;
    zhi[i] = (sh_ < SEQ) ? zsrc[(long)sh_ * 64] : 0u;
  }
  unsigned int csr[8];
  if (ACC) {
    #pragma unroll
    for (int i = 0; i < 8; ++i)
      csr[i] = *reinterpret_cast<const unsigned int*>(
          CSin + ((long)r0 + q * 8 + i) * DMODEL + 2 * p);
  }
  u32x4 wfr[4];
  #pragma unroll
  for (int it = 0; it < 4; ++it) {
    const int u = it * 512 + tid;
    const int e = u >> 4, g4 = u & 15;
    const float* wsrc = W3h + e * DMODEL + g4 * 8;
    float4 f0 = *reinterpret_cast<const float4*>(wsrc);
    float4 f1 = *reinterpret_cast<const float4*>(wsrc + 4);
    unsigned short o[8];
    o[0] = f2bf(f0.x); o[1] = f2bf(f0.y); o[2] = f2bf(f0.z); o[3] = f2bf(f0.w);
    o[4] = f2bf(f1.x); o[5] = f2bf(f1.y); o[6] = f2bf(f1.z); o[7] = f2bf(f1.w);
    wfr[it] = *reinterpret_cast<u32x4*>(o);
  }
  int etv = 1;
  if (tid < 64) etv = et[(long)b * SEQ + s0 + tid];
  if (tid < 64) {  // rowmean via wave-0 shuffle reduce
    #pragma unroll
    for (int t = 0; t < NTYPES; ++t) {
      float v = corm[t * DMODEL + tid] + corm[t * DMODEL + 64 + tid];
      #pragma unroll
      for (int o = 32; o > 0; o >>= 1) v += __shfl_xor(v, o, 64);
      if (tid == 0) rowmean[t] = v * (1.0f / DMODEL);
    }
  }

  // ---- phase 2: s8 partials from registers (groups q and q+8) ----
  {
    float a0 = 0.f, a1 = 0.f, b0 = 0.f, b1 = 0.f;
    #pragma unroll
    for (int i = 0; i < 8; ++i) {
      a0 += bflo(zlo[i]); a1 += bfhi(zlo[i]);
      b0 += bflo(zhi[i]); b1 += bfhi(zhi[i]);
    }
    s8[q * 64 + p] = make_float2(a0, a1);
    s8[(q + 8) * 64 + p] = make_float2(b0, b1);
  }
  __syncthreads();  // BAR1

  // ---- phase 3: window = sum s8 groups [q, q+8); g table ----
  float w0 = 0.f, w1 = 0.f;
  #pragma unroll
  for (int j = 0; j < 8; ++j) {
    const float2 v = s8[(q + j) * 64 + p];
    w0 += v.x; w1 += v.y;
  }
  if (tid < 64) g_lds[tid] = rowmean[etv - 1];
  __syncthreads();  // BAR2 (s8 dead -> Wl writable; g_lds visible)

  // ---- phase 4: Wl write from regs; slide 8 outputs/thread ----
  #pragma unroll
  for (int it = 0; it < 4; ++it) {
    const int u = it * 512 + tid;
    const int e = u >> 4, g4 = u & 15;
    *reinterpret_cast<u32x4*>(Wl + e * 272 + g4 * 16) = wfr[it];
  }
  float hs0 = 0.f, hs1 = 0.f;
  #pragma unroll
  for (int i = 0; i < 8; ++i) {
    const int s = q * 8 + i;
    const float c0v = w0, c1v = w1;
    const float g = g_lds[s];
    hs0 += c0v * g; hs1 += c1v * g;
    unsigned int pk;
    if (ACC)
      pk = pkbf(c0v + bflo(csr[i]), c1v + bfhi(csr[i]));
    else
      pk = pkbf(c0v, c1v);
    *reinterpret_cast<unsigned int*>(Cout + ((long)r0 + s) * DMODEL + 2 * p) = pk;
    *reinterpret_cast<unsigned int*>(Xl + s * 272 + p * 4) =
        ACC ? pkbf(c0v, c1v) : pk;
    w0 += bflo(zhi[i]) - bflo(zlo[i]);
    w1 += bfhi(zhi[i]) - bfhi(zlo[i]);
  }
  *reinterpret_cast<float2*>(hred + (p * 8 + q) * 2) = make_float2(hs0, hs1);
  __syncthreads();  // BAR3

  // ---- phase 5: hred reduce (q==0); MFMA -> Zout ----
  if (q == 0) {
    float t0 = 0.f, t1 = 0.f;
    #pragma unroll
    for (int k = 0; k < 8; ++k) {
      const float2 v = *reinterpret_cast<const float2*>(hred + (p * 8 + k) * 2);
      t0 += v.x; t1 += v.y;
    }
    atomicAdd(SH + b * DMODEL + 2 * p, t0);
    atomicAdd(SH + b * DMODEL + 2 * p + 1, t1);
  }
  const int wv = tid >> 6, l = tid & 63;
  const int mv = wv >> 1, nh = wv & 1;
  const int lr = l & 15, lk = l >> 4;
  f32x4 acc[4];
  #pragma unroll
  for (int n = 0; n < 4; ++n) acc[n] = (f32x4){0.f, 0.f, 0.f, 0.f};
  #pragma unroll
  for (int t = 0; t < 4; ++t) {
    const bf16x8 a = *reinterpret_cast<const bf16x8*>(
        Xl + (mv * 16 + lr) * 272 + (t * 4 + lk) * 16);
    #pragma unroll
    for (int n = 0; n < 4; ++n) {
      const bf16x8 bfrag = *reinterpret_cast<const bf16x8*>(
          Wl + (nh * 64 + n * 16 + lr) * 272 + (t * 4 + lk) * 16);
      acc[n] = __builtin_amdgcn_mfma_f32_16x16x32_bf16(a, bfrag, acc[n], 0, 0, 0);
    }
  }
  #pragma unroll
  for (int n = 0; n < 4; ++n) {
    const int col = nh * 64 + n * 16 + lr;
    const float bias = bvec[col];
    #pragma unroll
    for (int r = 0; r < 4; ++r) {
      const int row = r0 + mv * 16 + lk * 4 + r;
      float v = acc[n][r] + bias;
      const float e = expm1f(fminf(v, 0.f));
      v = v > 0.f ? v : e;
      Zout[(long)row * DMODEL + col] = f2bf(v);
    }
  }
}

// ---------------------------------------------------------------------------
// band3: register-resident band on z3; ss = corr3 + cs2 (f32) -> d_out.
// grid 512, 512 thr, LDS ~12.5 KB. 2 barriers + reduce.
// ---------------------------------------------------------------------------
__global__ __launch_bounds__(512, 4) void band3_kernel(
    const unsigned short* __restrict__ Zin,   // z3
    const unsigned short* __restrict__ CSin,  // cs2 = c0+c1+c2
    float* __restrict__ SS,
    float* __restrict__ SH,
    const int* __restrict__ et,
    const float* __restrict__ corm) {
  __shared__ float2 s8[16 * 64];     // 8192
  __shared__ float hred[64 * 8 * 2];  // 4096
  __shared__ float g_lds[64];
  __shared__ float rowmean[NTYPES];

  const int tid = threadIdx.x;
  const int swz = xcd_swz(blockIdx.x, gridDim.x);
  const int r0 = swz * 64;
  const int b = r0 >> 11, s0 = r0 & 2047;
  const int p = tid & 63, q = tid >> 6;

  const unsigned int* zsrc =
      reinterpret_cast<const unsigned int*>(Zin) + (long)b * SEQ * 64 + p;
  unsigned int zlo[8], zhi[8], csr[8];
  #pragma unroll
  for (int i = 0; i < 8; ++i) {
    const int sl = s0 + q * 8 + i;
    zlo[i] = zsrc[(long)sl * 64];
    const int sh_ = sl + BAND;
    zhi[i] = (sh_ < SEQ) ? zsrc[(long)sh_ * 64] : 0u;
    csr[i] = *reinterpret_cast<const unsigned int*>(
        CSin + ((long)r0 + q * 8 + i) * DMODEL + 2 * p);
  }
  int etv = 1;
  if (tid < 64) etv = et[(long)b * SEQ + s0 + tid];
  if (tid < 64) {
    #pragma unroll
    for (int t = 0; t < NTYPES; ++t) {
      float v = corm[t * DMODEL + tid] + corm[t * DMODEL + 64 + tid];
      #pragma unroll
      for (int o = 32; o > 0; o >>= 1) v += __shfl_xor(v, o, 64);
      if (tid == 0) rowmean[t] = v * (1.0f / DMODEL);
    }
  }
  {
    float a0 = 0.f, a1 = 0.f, b0 = 0.f, b1 = 0.f;
    #pragma unroll
    for (int i = 0; i < 8; ++i) {
      a0 += bflo(zlo[i]); a1 += bfhi(zlo[i]);
      b0 += bflo(zhi[i]); b1 += bfhi(zhi[i]);
    }
    s8[q * 64 + p] = make_float2(a0, a1);
    s8[(q + 8) * 64 + p] = make_float2(b0, b1);
  }
  __syncthreads();  // BAR1

  float w0 = 0.f, w1 = 0.f;
  #pragma unroll
  for (int j = 0; j < 8; ++j) {
    const float2 v = s8[(q + j) * 64 + p];
    w0 += v.x; w1 += v.y;
  }
  if (tid < 64) g_lds[tid] = rowmean[etv - 1];
  __syncthreads();  // BAR2 (g_lds visible)

  float hs0 = 0.f, hs1 = 0.f;
  #pragma unroll
  for (int i = 0; i < 8; ++i) {
    const int s = q * 8 + i;
    const float c0v = w0, c1v = w1;
    const float g = g_lds[s];
    hs0 += c0v * g; hs1 += c1v * g;
    float2 o;
    o.x = c0v + bflo(csr[i]);
    o.y = c1v + bfhi(csr[i]);
    *reinterpret_cast<float2*>(SS + ((long)r0 + s) * DMODEL + 2 * p) = o;
    w0 += bflo(zhi[i]) - bflo(zlo[i]);
    w1 += bfhi(zhi[i]) - bfhi(zlo[i]);
  }
  *reinterpret_cast<float2*>(hred + (p * 8 + q) * 2) = make_float2(hs0, hs1);
  __syncthreads();  // BAR3
  if (q == 0) {
    float t0 = 0.f, t1 = 0.f;
    #pragma unroll
    for (int k = 0; k < 8; ++k) {
      const float2 v = *reinterpret_cast<const float2*>(hred + (p * 8 + k) * 2);
      t0 += v.x; t1 += v.y;
    }
    atomicAdd(SH + b * DMODEL + 2 * p, t0);
    atomicAdd(SH + b * DMODEL + 2 * p + 1, t1);
  }
}

// ---------------------------------------------------------------------------
extern "C" void kernel_launch(void* const* d_in, const int* in_sizes, int n_in,
                              void* d_out, int out_size, void* d_ws, size_t ws_size,
                              hipStream_t stream) {
  const float* x0   = (const float*)d_in[0];
  // d_in[1] = local_cor (banded mask) -- structure known analytically, unused
  const float* corm = (const float*)d_in[2];
  const int*   et   = (const int*)d_in[3];
  const float* W3   = (const float*)d_in[4];
  const float* b3   = (const float*)d_in[5];

  float* out_ss = (float*)d_out;
  float* out_sh = out_ss + (size_t)MROWS * DMODEL;

  char* ws = (char*)d_ws;
  const size_t MB = 1024 * 1024;
  unsigned short* A = (unsigned short*)(ws + 0 * MB);   // z0, then z2
  unsigned short* B = (unsigned short*)(ws + 8 * MB);   // corr0
  unsigned short* C = (unsigned short*)(ws + 16 * MB);  // cs1
  unsigned short* D = (unsigned short*)(ws + 24 * MB);  // cs2
  unsigned short* E = (unsigned short*)(ws + 32 * MB);  // z1, then z3

  const size_t WSTR = (size_t)DMODEL * DMODEL;

  // gemm0 (+SH zero): z0 = A
  gemm0_kernel<<<512, 512, 0, stream>>>(x0, W3, b3, A, out_sh);
  // F0: band0 (z0=A) -> corr0=B ; gemm1 -> z1=E
  fused_band_gemm<0><<<512, 512, 0, stream>>>(
      A, nullptr, B, W3 + 1 * WSTR, b3 + 1 * DMODEL, E, out_sh, et, corm);
  // F1: band1 (z1=E) -> cs1=C (=corr0+corr1) ; gemm2 -> z2=A
  fused_band_gemm<1><<<512, 512, 0, stream>>>(
      E, B, C, W3 + 2 * WSTR, b3 + 2 * DMODEL, A, out_sh, et, corm);
  // F2: band2 (z2=A) -> cs2=D (=cs1+corr2) ; gemm3 -> z3=E
  fused_band_gemm<1><<<512, 512, 0, stream>>>(
      A, C, D, W3 + 3 * WSTR, b3 + 3 * DMODEL, E, out_sh, et, corm);
  // band3: ss = cs2 + corr3 -> d_out
  band3_kernel<<<512, 512, 0, stream>>>(E, D, out_ss, out_sh, et, corm);
}